// Round 8
// baseline (25857.834 us; speedup 1.0000x reference)
//
#include <hip/hip_runtime.h>

// Problem constants: B=4,S=128,E=512,H=8,Dh=64,V=32000,M=16,T=144,L=2,FF=2048
#define BB 4
#define SS 128
#define EE 512
#define HH 8
#define VV 32000
#define MM 16
#define TT 144
#define LL 2
#define FFF 2048
#define GRID 256   // 1 block/CU -> all blocks co-resident (LDS 53KB, 4 waves)

typedef short short8 __attribute__((ext_vector_type(8)));
typedef float f32x4 __attribute__((ext_vector_type(4)));

// f32 -> bf16 hi/lo split (RNE): x ~= hi + lo, |err| ~ 2^-17 |x|
__device__ __forceinline__ ushort bf16_rne(float x) {
    uint u = __float_as_uint(x);
    return (ushort)((u + 0x7FFF + ((u >> 16) & 1)) >> 16);
}
__device__ __forceinline__ void split2(float x, ushort& hs, ushort& ls) {
    hs = bf16_rne(x);
    const float hf = __uint_as_float((uint)hs << 16);
    ls = bf16_rne(x - hf);
}
__device__ __forceinline__ void split4(const float4 v, ushort4& h, ushort4& l) {
    split2(v.x, h.x, l.x); split2(v.y, h.y, l.y);
    split2(v.z, h.z, l.z); split2(v.w, h.w, l.w);
}

// ---------------------------------------------------------------------------
// Encoder kernels (one-time; unchanged from round 6)
// ---------------------------------------------------------------------------
__global__ __launch_bounds__(256) void split_kernel(
    const float* __restrict__ src, ushort* __restrict__ hi,
    ushort* __restrict__ lo, int n4)
{
    int i = blockIdx.x * 256 + threadIdx.x;
    const int stride = gridDim.x * 256;
    for (; i < n4; i += stride) {
        ushort4 h, l;
        split4(((const float4*)src)[i], h, l);
        ((ushort4*)hi)[i] = h;
        ((ushort4*)lo)[i] = l;
    }
}

__global__ __launch_bounds__(256, 2) void gemm_nt(
    const float* __restrict__ A, const int* __restrict__ Aidx, int lda,
    const float* __restrict__ W, const float* __restrict__ bias,
    float* __restrict__ C, int ldc, size_t pstride, int K, int Kslice)
{
    __shared__ float As[16][68];
    __shared__ float Ws[16][68];
    const int tid = threadIdx.x;
    const int tx = tid & 15, ty = tid >> 4;
    const int m0 = blockIdx.x * 64, n0 = blockIdx.y * 64;
    const int z = blockIdx.z;
    const int lrow = tid >> 2;
    const int lk = (tid & 3) << 2;
    const float* Arow;
    if (Aidx) Arow = A + (size_t)Aidx[m0 + lrow] * lda;
    else      Arow = A + (size_t)(m0 + lrow) * lda;
    const float* Wrow = W + (size_t)(n0 + lrow) * K;

    float acc[4][4];
#pragma unroll
    for (int i = 0; i < 4; i++)
#pragma unroll
        for (int j = 0; j < 4; j++) acc[i][j] = 0.f;

    const int kbeg = z * Kslice, kend = kbeg + Kslice;
    for (int k0 = kbeg; k0 < kend; k0 += 16) {
        const float4 av = *(const float4*)(Arow + k0 + lk);
        const float4 wv = *(const float4*)(Wrow + k0 + lk);
        __syncthreads();
        As[lk + 0][lrow] = av.x; As[lk + 1][lrow] = av.y;
        As[lk + 2][lrow] = av.z; As[lk + 3][lrow] = av.w;
        Ws[lk + 0][lrow] = wv.x; Ws[lk + 1][lrow] = wv.y;
        Ws[lk + 2][lrow] = wv.z; Ws[lk + 3][lrow] = wv.w;
        __syncthreads();
#pragma unroll
        for (int k = 0; k < 16; k++) {
            const float4 a = *(const float4*)(&As[k][ty << 2]);
            const float4 bq = *(const float4*)(&Ws[k][tx << 2]);
            acc[0][0] += a.x * bq.x; acc[0][1] += a.x * bq.y; acc[0][2] += a.x * bq.z; acc[0][3] += a.x * bq.w;
            acc[1][0] += a.y * bq.x; acc[1][1] += a.y * bq.y; acc[1][2] += a.y * bq.z; acc[1][3] += a.y * bq.w;
            acc[2][0] += a.z * bq.x; acc[2][1] += a.z * bq.y; acc[2][2] += a.z * bq.z; acc[2][3] += a.z * bq.w;
            acc[3][0] += a.w * bq.x; acc[3][1] += a.w * bq.y; acc[3][2] += a.w * bq.z; acc[3][3] += a.w * bq.w;
        }
    }

    float4 bv = make_float4(0.f, 0.f, 0.f, 0.f);
    if (bias && z == 0) bv = *(const float4*)(bias + n0 + (tx << 2));
    float* Cz = C + z * pstride;
#pragma unroll
    for (int i = 0; i < 4; i++) {
        const int r = m0 + (ty << 2) + i;
        float4 o;
        o.x = acc[i][0] + bv.x; o.y = acc[i][1] + bv.y;
        o.z = acc[i][2] + bv.z; o.w = acc[i][3] + bv.w;
        *(float4*)(Cz + (size_t)r * ldc + n0 + (tx << 2)) = o;
    }
}

__global__ __launch_bounds__(256) void reduce_kernel(
    const float* __restrict__ P, size_t pstride,
    float* __restrict__ out, int n4, int znum)
{
    int i = blockIdx.x * 256 + threadIdx.x;
    const int stride = gridDim.x * 256;
    for (; i < n4; i += stride) {
        float4 o = ((const float4*)P)[i];
        for (int zz = 1; zz < znum; zz++) {
            const float4 b = ((const float4*)(P + zz * pstride))[i];
            o.x += b.x; o.y += b.y; o.z += b.z; o.w += b.w;
        }
        ((float4*)out)[i] = o;
    }
}

// Encoder attention over split-K qkv partials (f32 out; planes writes unused).
template<int TK, int MODE, int NZ>
__global__ __launch_bounds__(256) void attn_kernel(
    const float* __restrict__ qkvP, size_t pstride,
    float* __restrict__ out, ushort* __restrict__ outH, ushort* __restrict__ outL,
    int T, int cur)
{
    __shared__ float KVs[TK][68];
    __shared__ float Qs[16][68];
    __shared__ float Ps[16][TK + 4];
    const int tid = threadIdx.x;
    const int tx = tid & 15, ty = tid >> 4;
    const int q0 = blockIdx.x * 16;
    const int h = blockIdx.y, b = blockIdx.z;
    const size_t base = (size_t)b * T * 1536 + h * 64;

    for (int idx = tid; idx < TK * 16; idx += 256) {
        const int j = idx >> 4, d4 = (idx & 15) << 2;
        const float* p = qkvP + base + (size_t)j * 1536 + 512 + d4;
        float4 v = *(const float4*)p;
#pragma unroll
        for (int zz = 1; zz < NZ; zz++) {
            const float4 u = *(const float4*)(p + zz * pstride);
            v.x += u.x; v.y += u.y; v.z += u.z; v.w += u.w;
        }
        *(float4*)&KVs[j][d4] = v;
    }
    {
        const int j = tid >> 4, d4 = (tid & 15) << 2;
        const float* p = qkvP + base + (size_t)(q0 + j) * 1536 + d4;
        float4 v = *(const float4*)p;
#pragma unroll
        for (int zz = 1; zz < NZ; zz++) {
            const float4 u = *(const float4*)(p + zz * pstride);
            v.x += u.x; v.y += u.y; v.z += u.z; v.w += u.w;
        }
        *(float4*)&Qs[j][d4] = v;
    }
    __syncthreads();

    const int qpos = q0 + ty;
    constexpr int NJ = TK >> 4;
    float s[NJ];
#pragma unroll
    for (int jj = 0; jj < NJ; jj++) {
        const int j = tx + (jj << 4);
        float acc = 0.f;
#pragma unroll
        for (int d = 0; d < 64; d += 4) {
            const float4 qv = *(const float4*)(&Qs[ty][d]);
            const float4 kv = *(const float4*)(&KVs[j][d]);
            acc += qv.x * kv.x + qv.y * kv.y + qv.z * kv.z + qv.w * kv.w;
        }
        acc *= 0.125f;
        if (MODE == 1 && j > qpos) acc += -1e9f;
        if (MODE == 2 && j >= cur) acc += -1e9f;
        s[jj] = acc;
    }
    float m = s[0];
#pragma unroll
    for (int jj = 1; jj < NJ; jj++) m = fmaxf(m, s[jj]);
#pragma unroll
    for (int o = 8; o >= 1; o >>= 1) m = fmaxf(m, __shfl_xor(m, o, 16));
    float sum = 0.f;
#pragma unroll
    for (int jj = 0; jj < NJ; jj++) {
        const float e = expf(s[jj] - m);
        s[jj] = e;
        sum += e;
    }
#pragma unroll
    for (int o = 8; o >= 1; o >>= 1) sum += __shfl_xor(sum, o, 16);
    const float inv = 1.f / sum;

    __syncthreads();

    for (int idx = tid; idx < TK * 16; idx += 256) {
        const int j = idx >> 4, d4 = (idx & 15) << 2;
        const float* p = qkvP + base + (size_t)j * 1536 + 1024 + d4;
        float4 v = *(const float4*)p;
#pragma unroll
        for (int zz = 1; zz < NZ; zz++) {
            const float4 u = *(const float4*)(p + zz * pstride);
            v.x += u.x; v.y += u.y; v.z += u.z; v.w += u.w;
        }
        *(float4*)&KVs[j][d4] = v;
    }
#pragma unroll
    for (int jj = 0; jj < NJ; jj++) Ps[ty][tx + (jj << 4)] = s[jj] * inv;
    __syncthreads();

    float4 o4 = make_float4(0.f, 0.f, 0.f, 0.f);
#pragma unroll 4
    for (int j = 0; j < TK; j++) {
        const float p = Ps[ty][j];
        const float4 v = *(const float4*)(&KVs[j][tx << 2]);
        o4.x = fmaf(p, v.x, o4.x); o4.y = fmaf(p, v.y, o4.y);
        o4.z = fmaf(p, v.z, o4.z); o4.w = fmaf(p, v.w, o4.w);
    }
    const size_t oidx = (size_t)(b * T + q0 + ty) * EE + h * 64 + (tx << 2);
    *(float4*)(out + oidx) = o4;
    ushort4 oh, ol;
    split4(o4, oh, ol);
    *(ushort4*)(outH + oidx) = oh;
    *(ushort4*)(outL + oidx) = ol;
}

__global__ __launch_bounds__(64) void embed_ln_kernel(
    const int* __restrict__ seq, const float* __restrict__ emb,
    const float* __restrict__ pemb, const float* __restrict__ g,
    const float* __restrict__ bta, float* __restrict__ out)
{
    const int r = blockIdx.x;
    const int s = r & (SS - 1);
    const int l = threadIdx.x;
    const int tok = seq[r];
    const float* er = emb + (size_t)tok * EE;
    const float* pr = pemb + (size_t)s * EE;
    float4 v[2];
    float sum = 0.f;
#pragma unroll
    for (int p = 0; p < 2; p++) {
        const int o = p * 256 + l * 4;
        const float4 a = *(const float4*)(er + o);
        const float4 c = *(const float4*)(pr + o);
        v[p] = make_float4(a.x + c.x, a.y + c.y, a.z + c.z, a.w + c.w);
        sum += v[p].x + v[p].y + v[p].z + v[p].w;
    }
#pragma unroll
    for (int o = 32; o >= 1; o >>= 1) sum += __shfl_xor(sum, o, 64);
    const float mean = sum * (1.f / EE);
    float vs = 0.f;
#pragma unroll
    for (int p = 0; p < 2; p++) {
        const float dx = v[p].x - mean, dy = v[p].y - mean;
        const float dz = v[p].z - mean, dw = v[p].w - mean;
        vs += dx * dx + dy * dy + dz * dz + dw * dw;
    }
#pragma unroll
    for (int o = 32; o >= 1; o >>= 1) vs += __shfl_xor(vs, o, 64);
    const float rstd = 1.f / sqrtf(vs * (1.f / EE) + 1e-5f);
#pragma unroll
    for (int p = 0; p < 2; p++) {
        const int o = p * 256 + l * 4;
        const float4 gv = *(const float4*)(g + o);
        const float4 bv = *(const float4*)(bta + o);
        float4 ov;
        ov.x = (v[p].x - mean) * rstd * gv.x + bv.x;
        ov.y = (v[p].y - mean) * rstd * gv.y + bv.y;
        ov.z = (v[p].z - mean) * rstd * gv.z + bv.z;
        ov.w = (v[p].w - mean) * rstd * gv.w + bv.w;
        *(float4*)(out + (size_t)r * EE + o) = ov;
    }
}

__global__ __launch_bounds__(256) void bufinit_kernel(
    const float* __restrict__ xe, float* __restrict__ buf,
    ushort* __restrict__ bufH, ushort* __restrict__ bufL)
{
    const int i = blockIdx.x * 256 + threadIdx.x;
    if (i >= BB * TT * EE / 4) return;
    const int g = i * 4;
    const int e = g & (EE - 1);
    const int t = (g >> 9) % TT;
    const int b = g / (EE * TT);
    float4 v = make_float4(0.f, 0.f, 0.f, 0.f);
    if (t < SS) v = *(const float4*)(xe + ((size_t)b * SS + t) * EE + e);
    ((float4*)buf)[i] = v;
    ushort4 h, l;
    split4(v, h, l);
    ((ushort4*)bufH)[i] = h;
    ((ushort4*)bufL)[i] = l;
}

// ---------------------------------------------------------------------------
// Persistent decoder mega-kernel: grid=256 (1/CU), custom device-scope barrier
// ---------------------------------------------------------------------------
struct SharedU {
    union {
        struct { ushort Ah[64][72], Al[64][72], Wh[64][72], Wl[64][72]; } g;   // 36,864 B
        struct { float KV[TT][68]; float Q[16][68]; float P[16][TT + 4]; } at; // 52,992 B
        struct { float last[BB][EE]; } lg;                                     //  8,192 B
        struct { float sv[256]; int si[256]; float wv[16]; int wi[16]; } red;
    };
};

struct MegaArgs {
    ushort *whi, *wlo;
    ushort *bufH, *bufL, *tgtH, *tgtL, *attH, *attL, *ffbH, *ffbL;
    float *buf, *tgt, *qkv, *sab, *Pff;
    float *pbv; int *pbi;
    uint *bcnt, *bgen;
    const float *dsi_b, *dso_b, *dci_b, *dco_b, *d1_b, *d2_b;
    const float *dln_g, *dln_b, *fo_w, *fo_b, *emb;
    int *out_tok;
};

// Sense-reversing grid barrier. Agent-scope atomics (per-XCD L2 non-coherent:
// plain spins could read stale lines; atomics go to the coherence point).
__device__ __forceinline__ void gbar(uint* cnt, uint* gen) {
    __syncthreads();
    if (threadIdx.x == 0) {
        __threadfence();
        const uint g = __hip_atomic_load(gen, __ATOMIC_RELAXED, __HIP_MEMORY_SCOPE_AGENT);
        const uint t = __hip_atomic_fetch_add(cnt, 1u, __ATOMIC_ACQ_REL, __HIP_MEMORY_SCOPE_AGENT);
        if (t == GRID - 1) {
            __hip_atomic_store(cnt, 0u, __ATOMIC_RELEASE, __HIP_MEMORY_SCOPE_AGENT);
            __hip_atomic_fetch_add(gen, 1u, __ATOMIC_ACQ_REL, __HIP_MEMORY_SCOPE_AGENT);
        } else {
            while (__hip_atomic_load(gen, __ATOMIC_ACQUIRE, __HIP_MEMORY_SCOPE_AGENT) == g)
                __builtin_amdgcn_s_sleep(2);
        }
        __threadfence();
    }
    __syncthreads();
}

// bf16x3 MFMA GEMM phase, block-strided tiles.
// EPI 0: f32 C + bias (z=1). EPI 1: relu+bias -> hi/lo planes (z=1).
// EPI 2: split-K z=4 partial f32 slices (bias only z==0).
template<int EPI>
__device__ void dgemm(SharedU& sh,
    const ushort* AqH, const ushort* AqL, const ushort* AkH, const ushort* AkL, int lda,
    const ushort* WH, const ushort* WL, const float* bias,
    float* C, ushort* CH, ushort* CL, int ldc, size_t pstride,
    int K, int Kslice, int TM, int TN)
{
    const int tid = threadIdx.x;
    const int l = tid & 63, w = tid >> 6;
    const int srow = tid >> 2, skb = (tid & 3) << 4;
    const int nz = (EPI == 2) ? 4 : 1;
    const int total = TM * TN * nz;
    for (int u = blockIdx.x; u < total; u += GRID) {
        int t = u, z = 0;
        if (EPI == 2) { z = u & 3; t = u >> 2; }
        const int m0 = (t / TN) * 64, n0 = (t % TN) * 64;
        const ushort* AH = (n0 < 512) ? AqH : AkH;
        const ushort* AL = (n0 < 512) ? AqL : AkL;
        const ushort* ArH = AH + (size_t)(m0 + srow) * lda;
        const ushort* ArL = AL + (size_t)(m0 + srow) * lda;
        const ushort* WrH = WH + (size_t)(n0 + srow) * K;
        const ushort* WrL = WL + (size_t)(n0 + srow) * K;

        f32x4 acc[4];
#pragma unroll
        for (int ns = 0; ns < 4; ns++) acc[ns] = (f32x4)0.f;

        const int kbeg = z * Kslice, kend = kbeg + Kslice;
        for (int k0 = kbeg; k0 < kend; k0 += 64) {
            const uint4 ah0 = *(const uint4*)(ArH + k0 + skb);
            const uint4 ah1 = *(const uint4*)(ArH + k0 + skb + 8);
            const uint4 al0 = *(const uint4*)(ArL + k0 + skb);
            const uint4 al1 = *(const uint4*)(ArL + k0 + skb + 8);
            const uint4 wh0 = *(const uint4*)(WrH + k0 + skb);
            const uint4 wh1 = *(const uint4*)(WrH + k0 + skb + 8);
            const uint4 wl0 = *(const uint4*)(WrL + k0 + skb);
            const uint4 wl1 = *(const uint4*)(WrL + k0 + skb + 8);
            __syncthreads();
            *(uint4*)&sh.g.Ah[srow][skb] = ah0; *(uint4*)&sh.g.Ah[srow][skb + 8] = ah1;
            *(uint4*)&sh.g.Al[srow][skb] = al0; *(uint4*)&sh.g.Al[srow][skb + 8] = al1;
            *(uint4*)&sh.g.Wh[srow][skb] = wh0; *(uint4*)&sh.g.Wh[srow][skb + 8] = wh1;
            *(uint4*)&sh.g.Wl[srow][skb] = wl0; *(uint4*)&sh.g.Wl[srow][skb + 8] = wl1;
            __syncthreads();
            const int fr = l & 15, fg = (l >> 4) << 3;
#pragma unroll
            for (int ks = 0; ks < 2; ks++) {
                const short8 a_h = *(const short8*)&sh.g.Ah[16 * w + fr][32 * ks + fg];
                const short8 a_l = *(const short8*)&sh.g.Al[16 * w + fr][32 * ks + fg];
#pragma unroll
                for (int ns = 0; ns < 4; ns++) {
                    const short8 b_h = *(const short8*)&sh.g.Wh[16 * ns + fr][32 * ks + fg];
                    const short8 b_l = *(const short8*)&sh.g.Wl[16 * ns + fr][32 * ks + fg];
                    acc[ns] = __builtin_amdgcn_mfma_f32_16x16x32_bf16(a_h, b_h, acc[ns], 0, 0, 0);
                    acc[ns] = __builtin_amdgcn_mfma_f32_16x16x32_bf16(a_h, b_l, acc[ns], 0, 0, 0);
                    acc[ns] = __builtin_amdgcn_mfma_f32_16x16x32_bf16(a_l, b_h, acc[ns], 0, 0, 0);
                }
            }
        }

        const int fr = l & 15, r4 = (l >> 4) << 2;
#pragma unroll
        for (int ns = 0; ns < 4; ns++) {
            const int col = n0 + 16 * ns + fr;
            float bc = 0.f;
            if (EPI != 2 || z == 0) bc = bias[col];
#pragma unroll
            for (int r = 0; r < 4; r++) {
                const int row = m0 + 16 * w + r4 + r;
                const float v = acc[ns][r] + bc;
                if (EPI == 0) {
                    C[(size_t)row * ldc + col] = v;
                } else if (EPI == 1) {
                    const float vr = fmaxf(v, 0.f);
                    ushort hs, ls;
                    split2(vr, hs, ls);
                    CH[(size_t)row * ldc + col] = hs;
                    CL[(size_t)row * ldc + col] = ls;
                } else {
                    (C + z * pstride)[(size_t)row * ldc + col] = v;
                }
            }
        }
    }
}

// Attention phase (TK=TT=144): 288 units (9 qtiles x 8 heads x 4 batch) -> planes
template<int MODE>
__device__ void dattn(SharedU& sh, const float* qkv,
                      ushort* outH, ushort* outL, int cur)
{
    const int tid = threadIdx.x;
    const int tx = tid & 15, ty = tid >> 4;
    for (int u = blockIdx.x; u < 288; u += GRID) {
        const int qt = u % 9;
        const int hb = u / 9;
        const int h = hb & 7, b = hb >> 3;
        const int q0 = qt * 16;
        const size_t base = (size_t)b * TT * 1536 + h * 64;
        __syncthreads();  // prior unit's LDS reads done before restaging
        for (int idx = tid; idx < TT * 16; idx += 256) {
            const int j = idx >> 4, d4 = (idx & 15) << 2;
            *(float4*)&sh.at.KV[j][d4] = *(const float4*)(qkv + base + (size_t)j * 1536 + 512 + d4);
        }
        {
            const int j = tid >> 4, d4 = (tid & 15) << 2;
            *(float4*)&sh.at.Q[j][d4] = *(const float4*)(qkv + base + (size_t)(q0 + j) * 1536 + d4);
        }
        __syncthreads();

        const int qpos = q0 + ty;
        float s[9];
#pragma unroll
        for (int jj = 0; jj < 9; jj++) {
            const int j = tx + (jj << 4);
            float acc = 0.f;
#pragma unroll
            for (int d = 0; d < 64; d += 4) {
                const float4 qv = *(const float4*)(&sh.at.Q[ty][d]);
                const float4 kv = *(const float4*)(&sh.at.KV[j][d]);
                acc += qv.x * kv.x + qv.y * kv.y + qv.z * kv.z + qv.w * kv.w;
            }
            acc *= 0.125f;
            if (MODE == 1 && j > qpos) acc += -1e9f;
            if (MODE == 2 && j >= cur) acc += -1e9f;
            s[jj] = acc;
        }
        float m = s[0];
#pragma unroll
        for (int jj = 1; jj < 9; jj++) m = fmaxf(m, s[jj]);
#pragma unroll
        for (int o = 8; o >= 1; o >>= 1) m = fmaxf(m, __shfl_xor(m, o, 16));
        float sum = 0.f;
#pragma unroll
        for (int jj = 0; jj < 9; jj++) {
            const float e = expf(s[jj] - m);
            s[jj] = e;
            sum += e;
        }
#pragma unroll
        for (int o = 8; o >= 1; o >>= 1) sum += __shfl_xor(sum, o, 16);
        const float inv = 1.f / sum;

        __syncthreads();
        for (int idx = tid; idx < TT * 16; idx += 256) {
            const int j = idx >> 4, d4 = (idx & 15) << 2;
            *(float4*)&sh.at.KV[j][d4] = *(const float4*)(qkv + base + (size_t)j * 1536 + 1024 + d4);
        }
#pragma unroll
        for (int jj = 0; jj < 9; jj++) sh.at.P[ty][tx + (jj << 4)] = s[jj] * inv;
        __syncthreads();

        float4 o4 = make_float4(0.f, 0.f, 0.f, 0.f);
#pragma unroll 4
        for (int j = 0; j < TT; j++) {
            const float p = sh.at.P[ty][j];
            const float4 v = *(const float4*)(&sh.at.KV[j][tx << 2]);
            o4.x = fmaf(p, v.x, o4.x); o4.y = fmaf(p, v.y, o4.y);
            o4.z = fmaf(p, v.z, o4.z); o4.w = fmaf(p, v.w, o4.w);
        }
        const size_t oidx = (size_t)(b * TT + q0 + ty) * EE + h * 64 + (tx << 2);
        ushort4 oh, ol;
        split4(o4, oh, ol);
        *(ushort4*)(outH + oidx) = oh;
        *(ushort4*)(outL + oidx) = ol;
    }
}

// Residual+LN phase: 576 rows, one wave per row, 4 rows per block -> 144 units
template<int NSUM>
__device__ void dresln(const float* X, const float* S, size_t pstride,
                       const float* g, const float* bta,
                       float* out, ushort* outH, ushort* outL)
{
    const int w = threadIdx.x >> 6, l = threadIdx.x & 63;
    for (int u = blockIdx.x; u < 144; u += GRID) {
        const int r = u * 4 + w;
        const float* xr = X + (size_t)r * EE;
        const float* sr = S + (size_t)r * EE;
        float4 v[2];
        float sum = 0.f;
#pragma unroll
        for (int p = 0; p < 2; p++) {
            const int o = p * 256 + l * 4;
            const float4 a = *(const float4*)(xr + o);
            float4 c = *(const float4*)(sr + o);
            if (NSUM == 4) {
                const float4 c1 = *(const float4*)(sr + pstride + o);
                const float4 c2 = *(const float4*)(sr + 2 * pstride + o);
                const float4 c3 = *(const float4*)(sr + 3 * pstride + o);
                c.x += c1.x + c2.x + c3.x; c.y += c1.y + c2.y + c3.y;
                c.z += c1.z + c2.z + c3.z; c.w += c1.w + c2.w + c3.w;
            }
            v[p] = make_float4(a.x + c.x, a.y + c.y, a.z + c.z, a.w + c.w);
            sum += v[p].x + v[p].y + v[p].z + v[p].w;
        }
#pragma unroll
        for (int o = 32; o >= 1; o >>= 1) sum += __shfl_xor(sum, o, 64);
        const float mean = sum * (1.f / EE);
        float vs = 0.f;
#pragma unroll
        for (int p = 0; p < 2; p++) {
            const float dx = v[p].x - mean, dy = v[p].y - mean;
            const float dz = v[p].z - mean, dw = v[p].w - mean;
            vs += dx * dx + dy * dy + dz * dz + dw * dw;
        }
#pragma unroll
        for (int o = 32; o >= 1; o >>= 1) vs += __shfl_xor(vs, o, 64);
        const float rstd = 1.f / sqrtf(vs * (1.f / EE) + 1e-5f);
#pragma unroll
        for (int p = 0; p < 2; p++) {
            const int o = p * 256 + l * 4;
            const float4 gv = *(const float4*)(g + o);
            const float4 bv = *(const float4*)(bta + o);
            float4 ov;
            ov.x = (v[p].x - mean) * rstd * gv.x + bv.x;
            ov.y = (v[p].y - mean) * rstd * gv.y + bv.y;
            ov.z = (v[p].z - mean) * rstd * gv.z + bv.z;
            ov.w = (v[p].w - mean) * rstd * gv.w + bv.w;
            const size_t oi = (size_t)r * EE + o;
            *(float4*)(out + oi) = ov;
            ushort4 oh, olo;
            split4(ov, oh, olo);
            *(ushort4*)(outH + oi) = oh;
            *(ushort4*)(outL + oi) = olo;
        }
    }
}

// Logits phase: 8000 groups of 4 cols, wave per col, per-block argmax partials.
__device__ void dlogits(SharedU& sh, const float* tgt,
                        const float* foW, const float* fob, int cur,
                        float* pbv, int* pbi)
{
    const int tid = threadIdx.x;
    for (int idx = tid; idx < 512; idx += 256) {   // 4 rows x 128 float4
        const int b = idx >> 7, e4 = idx & 127;
        ((float4*)sh.lg.last[b])[e4] =
            ((const float4*)(tgt + ((size_t)b * TT + (cur - 1)) * EE))[e4];
    }
    __syncthreads();
    const int w = tid >> 6, l = tid & 63;
    float bv0 = -3.4e38f, bv1 = -3.4e38f, bv2 = -3.4e38f, bv3 = -3.4e38f;
    int bi0 = 0x7fffffff, bi1 = 0x7fffffff, bi2 = 0x7fffffff, bi3 = 0x7fffffff;
    for (int grp = blockIdx.x; grp < VV / 4; grp += GRID) {
        const int col = grp * 4 + w;
        const float* wr = foW + (size_t)col * EE;
        float a0 = 0.f, a1 = 0.f, a2 = 0.f, a3 = 0.f;
#pragma unroll
        for (int p = 0; p < 2; p++) {
            const int o = p * 256 + l * 4;
            const float4 wv = *(const float4*)(wr + o);
            const float4 l0 = *(const float4*)(&sh.lg.last[0][o]);
            const float4 l1 = *(const float4*)(&sh.lg.last[1][o]);
            const float4 l2 = *(const float4*)(&sh.lg.last[2][o]);
            const float4 l3 = *(const float4*)(&sh.lg.last[3][o]);
            a0 += wv.x * l0.x + wv.y * l0.y + wv.z * l0.z + wv.w * l0.w;
            a1 += wv.x * l1.x + wv.y * l1.y + wv.z * l1.z + wv.w * l1.w;
            a2 += wv.x * l2.x + wv.y * l2.y + wv.z * l2.z + wv.w * l2.w;
            a3 += wv.x * l3.x + wv.y * l3.y + wv.z * l3.z + wv.w * l3.w;
        }
#pragma unroll
        for (int o = 32; o >= 1; o >>= 1) {
            a0 += __shfl_xor(a0, o, 64); a1 += __shfl_xor(a1, o, 64);
            a2 += __shfl_xor(a2, o, 64); a3 += __shfl_xor(a3, o, 64);
        }
        if (l == 0) {
            const float bb = fob[col];
            const float v0 = a0 + bb, v1 = a1 + bb, v2 = a2 + bb, v3 = a3 + bb;
            if (v0 > bv0) { bv0 = v0; bi0 = col; }
            if (v1 > bv1) { bv1 = v1; bi1 = col; }
            if (v2 > bv2) { bv2 = v2; bi2 = col; }
            if (v3 > bv3) { bv3 = v3; bi3 = col; }
        }
    }
    __syncthreads();   // done reading sh.lg; reuse union for wave combine
    if (l == 0) {
        sh.red.wv[w * 4 + 0] = bv0; sh.red.wi[w * 4 + 0] = bi0;
        sh.red.wv[w * 4 + 1] = bv1; sh.red.wi[w * 4 + 1] = bi1;
        sh.red.wv[w * 4 + 2] = bv2; sh.red.wi[w * 4 + 2] = bi2;
        sh.red.wv[w * 4 + 3] = bv3; sh.red.wi[w * 4 + 3] = bi3;
    }
    __syncthreads();
    if (tid < 4) {
        float bv = -3.4e38f; int bi = 0x7fffffff;
#pragma unroll
        for (int ww = 0; ww < 4; ww++) {
            const float v = sh.red.wv[ww * 4 + tid];
            const int ix = sh.red.wi[ww * 4 + tid];
            if (v > bv || (v == bv && ix < bi)) { bv = v; bi = ix; }
        }
        pbv[blockIdx.x * 4 + tid] = bv;
        pbi[blockIdx.x * 4 + tid] = bi;
    }
}

// Final argmax over 256 block partials; write token; append embedding row.
__device__ void dargmax(SharedU& sh, const float* pbv, const int* pbi,
                        const float* emb, float* buf, ushort* bufH, ushort* bufL,
                        int* out_tok, int cur, int step)
{
    if (blockIdx.x >= 4) return;
    const int b = blockIdx.x;
    const int tid = threadIdx.x;
    sh.red.sv[tid] = pbv[tid * 4 + b];
    sh.red.si[tid] = pbi[tid * 4 + b];
    __syncthreads();
    for (int s = 128; s > 0; s >>= 1) {
        if (tid < s) {
            const float xo = sh.red.sv[tid + s]; const int io = sh.red.si[tid + s];
            if (xo > sh.red.sv[tid] || (xo == sh.red.sv[tid] && io < sh.red.si[tid])) {
                sh.red.sv[tid] = xo; sh.red.si[tid] = io;
            }
        }
        __syncthreads();
    }
    const int tok = sh.red.si[0];
    if (tid == 0) out_tok[b * MM + step] = tok;
    if (tid < 128) {
        const float4 v = *(const float4*)(emb + (size_t)tok * EE + tid * 4);
        const size_t oi = ((size_t)b * TT + cur) * EE + tid * 4;
        *(float4*)(buf + oi) = v;
        ushort4 h, l;
        split4(v, h, l);
        *(ushort4*)(bufH + oi) = h;
        *(ushort4*)(bufL + oi) = l;
    }
}

// weight plane offsets (elements)
#define O_DSI 0u
#define O_DSO 1572864u
#define O_DCI 2097152u
#define O_DCO 3670016u
#define O_D1  4194304u
#define O_D2  6291456u

__global__ __launch_bounds__(256) void mega_decoder(MegaArgs a)
{
    __shared__ SharedU sh;
    const size_t psD = (size_t)BB * TT * EE;   // 294,912
    for (int i = 0; i < MM; i++) {
        const int cur = SS + i;
        for (int l = 0; l < LL; l++) {
            const float*  tinF = l ? a.tgt  : a.buf;
            const ushort* tinH = l ? a.tgtH : a.bufH;
            const ushort* tinL = l ? a.tgtL : a.bufL;
            const size_t wl1536 = (size_t)l * 1536 * EE;
            const size_t wl512  = (size_t)l * EE * EE;
            const size_t wlF    = (size_t)l * FFF * EE;
            // P1: qkv (self) = tin @ Wsi^T + b  -> qkv f32 [576,1536]
            dgemm<0>(sh, tinH, tinL, tinH, tinL, EE,
                     a.whi + O_DSI + wl1536, a.wlo + O_DSI + wl1536, a.dsi_b + l * 1536,
                     a.qkv, nullptr, nullptr, 1536, 0, 512, 512, 9, 24);
            gbar(a.bcnt, a.bgen);
            // P2: causal attn -> att planes
            dattn<1>(sh, a.qkv, a.attH, a.attL, cur);
            gbar(a.bcnt, a.bgen);
            // P3: out-proj -> sab f32
            dgemm<0>(sh, a.attH, a.attL, a.attH, a.attL, EE,
                     a.whi + O_DSO + wl512, a.wlo + O_DSO + wl512, a.dso_b + l * EE,
                     a.sab, nullptr, nullptr, EE, 0, 512, 512, 9, 8);
            gbar(a.bcnt, a.bgen);
            // P4: tgt = LN(tin + sab)
            dresln<1>(tinF, a.sab, 0, a.dln_g + (l * 3 + 0) * EE, a.dln_b + (l * 3 + 0) * EE,
                      a.tgt, a.tgtH, a.tgtL);
            gbar(a.bcnt, a.bgen);
            // P5: qkv (cross): q from tgt, kv from buf
            dgemm<0>(sh, a.tgtH, a.tgtL, a.bufH, a.bufL, EE,
                     a.whi + O_DCI + wl1536, a.wlo + O_DCI + wl1536, a.dci_b + l * 1536,
                     a.qkv, nullptr, nullptr, 1536, 0, 512, 512, 9, 24);
            gbar(a.bcnt, a.bgen);
            // P6: key-limited attn -> att planes
            dattn<2>(sh, a.qkv, a.attH, a.attL, cur);
            gbar(a.bcnt, a.bgen);
            // P7: out-proj -> sab
            dgemm<0>(sh, a.attH, a.attL, a.attH, a.attL, EE,
                     a.whi + O_DCO + wl512, a.wlo + O_DCO + wl512, a.dco_b + l * EE,
                     a.sab, nullptr, nullptr, EE, 0, 512, 512, 9, 8);
            gbar(a.bcnt, a.bgen);
            // P8: tgt = LN(tgt + sab)
            dresln<1>(a.tgt, a.sab, 0, a.dln_g + (l * 3 + 1) * EE, a.dln_b + (l * 3 + 1) * EE,
                      a.tgt, a.tgtH, a.tgtL);
            gbar(a.bcnt, a.bgen);
            // P9: ffn1 + relu -> ffb planes [576,2048]
            dgemm<1>(sh, a.tgtH, a.tgtL, a.tgtH, a.tgtL, EE,
                     a.whi + O_D1 + wlF, a.wlo + O_D1 + wlF, a.d1_b + l * FFF,
                     nullptr, a.ffbH, a.ffbL, FFF, 0, 512, 512, 9, 32);
            gbar(a.bcnt, a.bgen);
            // P10: ffn2 split-K x4 -> Pff partial slices
            dgemm<2>(sh, a.ffbH, a.ffbL, a.ffbH, a.ffbL, FFF,
                     a.whi + O_D2 + wlF, a.wlo + O_D2 + wlF, a.d2_b + l * EE,
                     a.Pff, nullptr, nullptr, EE, psD, 2048, 512, 9, 8);
            gbar(a.bcnt, a.bgen);
            // P11: tgt = LN(tgt + sum4 Pff)
            dresln<4>(a.tgt, a.Pff, psD, a.dln_g + (l * 3 + 2) * EE, a.dln_b + (l * 3 + 2) * EE,
                      a.tgt, a.tgtH, a.tgtL);
            gbar(a.bcnt, a.bgen);
        }
        // P12: logits + per-block argmax partials
        dlogits(sh, a.tgt, a.fo_w, a.fo_b, cur, a.pbv, a.pbi);
        gbar(a.bcnt, a.bgen);
        // P13: final argmax, write token, append embedding to buf
        dargmax(sh, a.pbv, a.pbi, a.emb, a.buf, a.bufH, a.bufL, a.out_tok, cur, i);
        gbar(a.bcnt, a.bgen);
    }
}

extern "C" void kernel_launch(void* const* d_in, const int* in_sizes, int n_in,
                              void* d_out, int out_size, void* d_ws, size_t ws_size,
                              hipStream_t stream)
{
    (void)in_sizes; (void)n_in; (void)out_size; (void)ws_size;
    const int*   seq   = (const int*)d_in[0];
    const int*   ptag  = (const int*)d_in[1];
    const int*   ntag  = (const int*)d_in[2];
    const float* emb   = (const float*)d_in[4];
    const float* pemb  = (const float*)d_in[5];
    const float* fcp_w = (const float*)d_in[6];
    const float* fcp_b = (const float*)d_in[7];
    const float* fcn_w = (const float*)d_in[8];
    const float* fcn_b = (const float*)d_in[9];
    const float* ln_g  = (const float*)d_in[10];
    const float* ln_b  = (const float*)d_in[11];
    const float* asi_w = (const float*)d_in[12];
    const float* asi_b = (const float*)d_in[13];
    const float* aso_w = (const float*)d_in[14];
    const float* aso_b = (const float*)d_in[15];
    const float* api_w = (const float*)d_in[16];
    const float* api_b = (const float*)d_in[17];
    const float* apo_w = (const float*)d_in[18];
    const float* apo_b = (const float*)d_in[19];
    const float* ani_w = (const float*)d_in[20];
    const float* ani_b = (const float*)d_in[21];
    const float* ano_w = (const float*)d_in[22];
    const float* ano_b = (const float*)d_in[23];
    const float* dsi_w = (const float*)d_in[24];
    const float* dsi_b = (const float*)d_in[25];
    const float* dso_w = (const float*)d_in[26];
    const float* dso_b = (const float*)d_in[27];
    const float* dci_w = (const float*)d_in[28];
    const float* dci_b = (const float*)d_in[29];
    const float* dco_w = (const float*)d_in[30];
    const float* dco_b = (const float*)d_in[31];
    const float* d1_w  = (const float*)d_in[32];
    const float* d1_b  = (const float*)d_in[33];
    const float* d2_w  = (const float*)d_in[34];
    const float* d2_b  = (const float*)d_in[35];
    const float* dln_g = (const float*)d_in[36];
    const float* dln_b = (const float*)d_in[37];
    const float* fo_w  = (const float*)d_in[38];
    const float* fo_b  = (const float*)d_in[39];
    int* out_tok = (int*)d_out;

    // ---- workspace layout ----
    ushort* us = (ushort*)d_ws;
    ushort* whi  = us;                        // 8,388,608
    ushort* wlo  = whi + 8388608;             // 8,388,608
    ushort* bufH = wlo + 8388608;             // 294,912 each below
    ushort* bufL = bufH + 294912;
    ushort* tgtH = bufL + 294912;
    ushort* tgtL = tgtH + 294912;
    ushort* attH = tgtL + 294912;
    ushort* attL = attH + 294912;
    ushort* ffbH = attL + 294912;             // 1,179,648
    ushort* ffbL = ffbH + 1179648;
    float* arena = (float*)(ffbL + 1179648);
    float* P    = arena;                      // 3,145,728 (encoder partials)
    float* qkv  = P;                          // decoder aliases inside P:
    float* sab  = P + 884736;                 //   884,736 + 294,912
    float* Pff  = P + 884736 + 294912;        //   + 1,179,648 = 2,359,296 <= P
    float* src  = P + 3145728;                // 262,144
    float* xe   = src + 262144;
    float* pf   = xe + 262144;
    float* nf   = pf + 262144;
    float* att  = nf + 262144;                // 294,912 (encoder attn f32)
    float* tgt  = att + 294912;               // 294,912
    float* buf  = tgt + 294912;               // 294,912
    float* pbv  = buf + 294912;               // 1,024
    int*   pbi  = (int*)(pbv + 1024);         // 1,024
    uint*  bcnt = (uint*)(pbi + 1024);
    uint*  bgen = bcnt + 1;

    const int RS = BB * SS;   // 512
    const size_t psE  = (size_t)RS * EE;      // 262,144
    const size_t psEq = (size_t)RS * 1536;    // 786,432

    // ---- one-time: split decoder weights into bf16 hi/lo planes ----
    split_kernel<<<512, 256, 0, stream>>>(dsi_w, whi + O_DSI, wlo + O_DSI, 1572864 / 4);
    split_kernel<<<256, 256, 0, stream>>>(dso_w, whi + O_DSO, wlo + O_DSO, 524288 / 4);
    split_kernel<<<512, 256, 0, stream>>>(dci_w, whi + O_DCI, wlo + O_DCI, 1572864 / 4);
    split_kernel<<<256, 256, 0, stream>>>(dco_w, whi + O_DCO, wlo + O_DCO, 524288 / 4);
    split_kernel<<<512, 256, 0, stream>>>(d1_w, whi + O_D1, wlo + O_D1, 2097152 / 4);
    split_kernel<<<512, 256, 0, stream>>>(d2_w, whi + O_D2, wlo + O_D2, 2097152 / 4);

    // ---------------- encoder (f32 path, runs once) ----------------
    embed_ln_kernel<<<RS, 64, 0, stream>>>(seq, emb, pemb, ln_g, ln_b, src);
    gemm_nt<<<dim3(RS / 64, 8, 4), 256, 0, stream>>>(emb, ptag, EE, fcp_w, fcp_b, P, EE, psE, EE, 128);
    reduce_kernel<<<256, 256, 0, stream>>>(P, psE, pf, 65536, 4);
    gemm_nt<<<dim3(RS / 64, 8, 4), 256, 0, stream>>>(emb, ntag, EE, fcn_w, fcn_b, P, EE, psE, EE, 128);
    reduce_kernel<<<256, 256, 0, stream>>>(P, psE, nf, 65536, 4);
    gemm_nt<<<dim3(RS / 64, 24, 4), 256, 0, stream>>>(src, nullptr, EE, asi_w, asi_b, P, 1536, psEq, EE, 128);
    attn_kernel<SS, 0, 4><<<dim3(SS / 16, HH, BB), 256, 0, stream>>>(P, psEq, att, attH, attL, SS, 0);
    gemm_nt<<<dim3(RS / 64, 8, 4), 256, 0, stream>>>(att, nullptr, EE, aso_w, aso_b, P, EE, psE, EE, 128);
    reduce_kernel<<<256, 256, 0, stream>>>(P, psE, xe, 65536, 4);
    gemm_nt<<<dim3(RS / 64, 8, 4), 256, 0, stream>>>(xe, nullptr, EE, api_w, api_b, P, 1536, psEq, EE, 128);
    gemm_nt<<<dim3(RS / 64, 16, 4), 256, 0, stream>>>(pf, nullptr, EE, api_w + 512 * EE, api_b + 512, P + 512, 1536, psEq, EE, 128);
    attn_kernel<SS, 0, 4><<<dim3(SS / 16, HH, BB), 256, 0, stream>>>(P, psEq, att, attH, attL, SS, 0);
    gemm_nt<<<dim3(RS / 64, 8, 4), 256, 0, stream>>>(att, nullptr, EE, apo_w, apo_b, P, EE, psE, EE, 128);
    reduce_kernel<<<256, 256, 0, stream>>>(P, psE, src, 65536, 4);
    gemm_nt<<<dim3(RS / 64, 8, 4), 256, 0, stream>>>(src, nullptr, EE, ani_w, ani_b, P, 1536, psEq, EE, 128);
    gemm_nt<<<dim3(RS / 64, 16, 4), 256, 0, stream>>>(nf, nullptr, EE, ani_w + 512 * EE, ani_b + 512, P + 512, 1536, psEq, EE, 128);
    attn_kernel<SS, 0, 4><<<dim3(SS / 16, HH, BB), 256, 0, stream>>>(P, psEq, att, attH, attL, SS, 0);
    gemm_nt<<<dim3(RS / 64, 8, 4), 256, 0, stream>>>(att, nullptr, EE, ano_w, ano_b, P, EE, psE, EE, 128);
    reduce_kernel<<<256, 256, 0, stream>>>(P, psE, xe, 65536, 4);
    bufinit_kernel<<<(BB * TT * EE / 4 + 255) / 256, 256, 0, stream>>>(xe, buf, bufH, bufL);

    // ---------------- decoder: one persistent kernel ----------------
    hipMemsetAsync(bcnt, 0, 2 * sizeof(uint), stream);   // barrier state
    MegaArgs a;
    a.whi = whi; a.wlo = wlo;
    a.bufH = bufH; a.bufL = bufL; a.tgtH = tgtH; a.tgtL = tgtL;
    a.attH = attH; a.attL = attL; a.ffbH = ffbH; a.ffbL = ffbL;
    a.buf = buf; a.tgt = tgt; a.qkv = qkv; a.sab = sab; a.Pff = Pff;
    a.pbv = pbv; a.pbi = pbi; a.bcnt = bcnt; a.bgen = bgen;
    a.dsi_b = dsi_b; a.dso_b = dso_b; a.dci_b = dci_b; a.dco_b = dco_b;
    a.d1_b = d1_b; a.d2_b = d2_b; a.dln_g = dln_g; a.dln_b = dln_b;
    a.fo_w = fo_w; a.fo_b = fo_b; a.emb = emb; a.out_tok = out_tok;
    mega_decoder<<<GRID, 256, 0, stream>>>(a);
}